// Round 8
// baseline (154.473 us; speedup 1.0000x reference)
//
#include <hip/hip_runtime.h>
#include <hip/hip_cooperative_groups.h>
#include <hip/hip_bf16.h>
#include <math.h>

namespace cg = cooperative_groups;

#define B_   2
#define N_   512
#define FN   128
#define FE   16
#define MID_ 128

typedef __attribute__((ext_vector_type(8)))  short short8_t;
typedef __attribute__((ext_vector_type(16))) float f32x16;

__device__ __forceinline__ short f2bf(float f) {
    __bf16 h = (__bf16)f;                    // fptrunc -> RNE bf16
    return __builtin_bit_cast(short, h);
}

// ---------------------------------------------------------------------------
// kFused: one cooperative kernel, 3 phases, 2 grid.sync()s.
// grid 512 x 256 thr, launch_bounds(256,2) -> 2 blocks/CU (co-residency 512 ✓),
// LDS 16.6 KB, VGPR ≤ 256 (phase-B peak ~80, no spills).
// Phase A (=kA): 512 blocks x 2 rows: msg1c/msg2/h1.
// Phase B (=kB): 4 waves = 4 mt, wave sweeps all 32 i of its chunk ->
//                no cross-wave merge; epilogue from registers.
// Phase C (=kC): final 16-partial max + h1 + msgs@Wo2 + bo2.
// ---------------------------------------------------------------------------
__global__ __launch_bounds__(256, 2) void kFused(
    const float* __restrict__ feat, const float* __restrict__ ef,
    const float* __restrict__ gfeat, const float* __restrict__ adj,
    const float* __restrict__ W1, const float* __restrict__ b1,
    const float* __restrict__ W2, const float* __restrict__ b2,
    const float* __restrict__ We, const float* __restrict__ be,
    const float* __restrict__ Wg, const float* __restrict__ bg,
    const float* __restrict__ Wo1, const float* __restrict__ bo1,
    const float* __restrict__ Wo2, const float* __restrict__ bo2,
    float* __restrict__ msg1c, float* __restrict__ msg2, float* __restrict__ h1,
    float* __restrict__ part, float* __restrict__ out)
{
    __shared__ __align__(16) float smem[32 * MID_];   // 16 KB, reused per phase
    __shared__ unsigned madj[32];
    __shared__ float    anyzf[32];

    cg::grid_group grid = cg::this_grid();
    const int bid = blockIdx.x;
    const int t   = threadIdx.x;

    // ================= Phase A =================
    {
        float* fl = smem;
        const int b  = bid >> 8;
        const int n0 = (bid & 255) * 2;
        const int r  = t >> 7, m = t & 127;

        if (t < 64)
            ((float4*)fl)[t] = ((const float4*)(feat + (size_t)(b * N_ + n0) * FN))[t];
        __syncthreads();

        const float* gb = gfeat + b * FN;
        float a1 = 0.f, a2 = 0.f, a3 = 0.f, mg = 0.f;
        for (int k0 = 0; k0 < FN; k0 += 8) {
            float w1v[8], w2v[8], w3v[8], wgv[8];
            #pragma unroll
            for (int u = 0; u < 8; ++u) {
                w1v[u] = W1 [(k0 + u) * MID_ + m];
                w2v[u] = W2 [(k0 + u) * MID_ + m];
                w3v[u] = Wo1[(k0 + u) * MID_ + m];
                wgv[u] = Wg [(k0 + u) * MID_ + m];
            }
            #pragma unroll
            for (int u = 0; u < 8; ++u) {
                const float f = fl[r * FN + k0 + u];
                a1 += f * w1v[u];
                a2 += f * w2v[u];
                a3 += f * w3v[u];
                mg += gb[k0 + u] * wgv[u];
            }
        }
        const size_t idx = (size_t)(b * N_ + n0 + r) * MID_ + m;
        msg1c[idx] = a1 + b1[m] + mg + bg[m] + be[m];
        msg2[idx]  = a2 + b2[m];
        h1[idx]    = a3 + bo1[m];
    }

    grid.sync();

    // ================= Phase B =================
    {
        float* m2l = smem;                 // [32 i][128 m]
        const int b   = bid >> 8;
        const int jt  = (bid >> 4) & 15;
        const int ic  = bid & 15;
        const int j0  = jt * 32, i0 = ic * 32;
        const int lane = t & 63, wid = t >> 6;   // 4 waves
        const int mt   = wid;
        const int g    = lane >> 5, lm = lane & 31;

        // stage msg2 chunk (coalesced float4)
        {
            const float4* src = (const float4*)(msg2 + (size_t)(b * N_ + i0) * MID_);
            #pragma unroll
            for (int q = 0; q < 4; ++q)
                ((float4*)m2l)[t + 256 * q] = src[t + 256 * q];
        }
        // adj -> bitmasks via ballot (wave covers 8 i via 4 ballots)
        #pragma unroll
        for (int p = 0; p < 4; ++p) {
            const int i_l = wid * 8 + 2 * p + g;
            const float av = adj[(size_t)(b * N_ + i0 + i_l) * N_ + j0 + lm];
            const unsigned long long bal = __ballot(av != 0.0f);
            if (lane == 0)  madj[wid * 8 + 2 * p]     = (unsigned)bal;
            if (lane == 32) madj[wid * 8 + 2 * p + 1] = (unsigned)(bal >> 32);
        }
        // B fragment for this wave's mt
        short8_t Bf;
        #pragma unroll
        for (int jj = 0; jj < 8; ++jj)
            Bf[jj] = f2bf(We[(8 * g + jj) * MID_ + mt * 32 + lm]);

        f32x16 accm;
        #pragma unroll
        for (int r = 0; r < 16; ++r) accm[r] = -INFINITY;

        __syncthreads();                   // madj, m2l published

        if (t < 32) {                      // all-ones column -> -inf floor, else 0
            unsigned ao = 0xFFFFFFFFu;
            #pragma unroll
            for (int i2 = 0; i2 < 32; ++i2) ao &= madj[i2];
            anyzf[t] = ((ao >> t) & 1u) ? -INFINITY : 0.0f;
        }
        __syncthreads();                   // anyzf published

        const float* efr = ef + ((size_t)(b * N_ + i0) * N_ + j0 + lm) * FE + 8 * g;
        #pragma unroll 2
        for (int ii = 0; ii < 32; ++ii) {
            const float4 ea = *(const float4*)efr;
            const float4 eb = *(const float4*)(efr + 4);
            efr += (size_t)N_ * FE;
            short8_t Af;
            Af[0] = f2bf(ea.x); Af[1] = f2bf(ea.y); Af[2] = f2bf(ea.z); Af[3] = f2bf(ea.w);
            Af[4] = f2bf(eb.x); Af[5] = f2bf(eb.y); Af[6] = f2bf(eb.z); Af[7] = f2bf(eb.w);

            const unsigned vmg = madj[ii] >> (4 * g);
            const float m2v = m2l[ii * MID_ + mt * 32 + lm];
            f32x16 C;
            #pragma unroll
            for (int r = 0; r < 16; ++r) {
                const int cr = (r & 3) + 8 * (r >> 2);
                C[r] = (vmg & (1u << cr)) ? m2v : -INFINITY;
            }
            const f32x16 S = __builtin_amdgcn_mfma_f32_32x32x16_bf16(Af, Bf, C, 0, 0, 0);
            #pragma unroll
            for (int r = 0; r < 16; ++r) accm[r] = fmaxf(accm[r], S[r]);
        }

        // epilogue straight from registers: +c1, 0-floor, store partial
        #pragma unroll
        for (int r = 0; r < 16; ++r) {
            const int jrow = (r & 3) + 8 * (r >> 2) + 4 * g;
            const float c1v = msg1c[(size_t)(b * N_ + j0 + jrow) * MID_ + mt * 32 + lm];
            const float v = fmaxf(accm[r] + c1v, anyzf[jrow]);
            part[((size_t)(ic * 2 + b) * N_ + j0 + jrow) * MID_ + mt * 32 + lm] = v;
        }
    }

    grid.sync();

    // ================= Phase C =================
    {
        float* ms = smem;
        const int b  = bid >> 8;
        const int j0 = (bid & 255) * 2;
        const int r  = t >> 7, m = t & 127;
        const size_t base = ((size_t)b * N_ + j0 + r) * MID_ + m;

        float u = -INFINITY;
        #pragma unroll
        for (int icc = 0; icc < 16; ++icc)
            u = fmaxf(u, part[(size_t)icc * 2 * N_ * MID_ + base]);
        ms[r * MID_ + m] = u;
        __syncthreads();

        float acc = h1[base] + bo2[m];
        for (int k0 = 0; k0 < MID_; k0 += 8) {
            float wv[8];
            #pragma unroll
            for (int uu = 0; uu < 8; ++uu) wv[uu] = Wo2[(k0 + uu) * MID_ + m];
            #pragma unroll
            for (int uu = 0; uu < 8; ++uu) acc += ms[r * MID_ + k0 + uu] * wv[uu];
        }
        out[base] = acc;
    }
}

// ===========================================================================
// Fallback path (round-7 kernels, proven): used only if cooperative launch
// is rejected (e.g. by graph capture). Outputs are identical.
// ===========================================================================
__global__ __launch_bounds__(256, 2) void kA(
    const float* __restrict__ feat, const float* __restrict__ gfeat,
    const float* __restrict__ W1, const float* __restrict__ b1,
    const float* __restrict__ W2, const float* __restrict__ b2,
    const float* __restrict__ be,
    const float* __restrict__ Wg, const float* __restrict__ bg,
    const float* __restrict__ Wo1, const float* __restrict__ bo1,
    float* __restrict__ msg1c, float* __restrict__ msg2, float* __restrict__ h1)
{
    __shared__ float fl[2 * FN];
    const int bid = blockIdx.x;
    const int b   = bid >> 8;
    const int n0  = (bid & 255) * 2;
    const int t   = threadIdx.x;
    const int r   = t >> 7, m = t & 127;

    if (t < 64)
        ((float4*)fl)[t] = ((const float4*)(feat + (size_t)(b * N_ + n0) * FN))[t];
    __syncthreads();

    const float* gb = gfeat + b * FN;
    float a1 = 0.f, a2 = 0.f, a3 = 0.f, mg = 0.f;
    for (int k0 = 0; k0 < FN; k0 += 8) {
        float w1v[8], w2v[8], w3v[8], wgv[8];
        #pragma unroll
        for (int u = 0; u < 8; ++u) {
            w1v[u] = W1 [(k0 + u) * MID_ + m];
            w2v[u] = W2 [(k0 + u) * MID_ + m];
            w3v[u] = Wo1[(k0 + u) * MID_ + m];
            wgv[u] = Wg [(k0 + u) * MID_ + m];
        }
        #pragma unroll
        for (int u = 0; u < 8; ++u) {
            const float f = fl[r * FN + k0 + u];
            a1 += f * w1v[u];
            a2 += f * w2v[u];
            a3 += f * w3v[u];
            mg += gb[k0 + u] * wgv[u];
        }
    }
    const size_t idx = (size_t)(b * N_ + n0 + r) * MID_ + m;
    msg1c[idx] = a1 + b1[m] + mg + bg[m] + be[m];
    msg2[idx]  = a2 + b2[m];
    h1[idx]    = a3 + bo1[m];
}

__global__ __launch_bounds__(512, 4) void kB(
    const float* __restrict__ ef, const float* __restrict__ adj,
    const float* __restrict__ We,
    const float* __restrict__ msg1c, const float* __restrict__ msg2,
    float* __restrict__ part)
{
    __shared__ float    m2l[32 * MID_];
    __shared__ float    mtile[4][32 * 32];
    __shared__ unsigned madj[32];
    __shared__ float    anyzf[32];

    const int bid = blockIdx.x;
    const int b   = bid >> 8;
    const int jt  = (bid >> 4) & 15;
    const int ic  = bid & 15;
    const int j0  = jt * 32, i0 = ic * 32;
    const int t    = threadIdx.x;
    const int lane = t & 63, wid = t >> 6;
    const int mt   = wid & 3, ih = wid >> 2;
    const int g    = lane >> 5, lm = lane & 31;

    {
        const float4* src = (const float4*)(msg2 + (size_t)(b * N_ + i0) * MID_);
        ((float4*)m2l)[t]       = src[t];
        ((float4*)m2l)[t + 512] = src[t + 512];
    }
    #pragma unroll
    for (int p = 0; p < 2; ++p) {
        const int i_l = wid * 4 + 2 * p + g;
        const float av = adj[(size_t)(b * N_ + i0 + i_l) * N_ + j0 + lm];
        const unsigned long long bal = __ballot(av != 0.0f);
        if (lane == 0)  madj[wid * 4 + 2 * p]     = (unsigned)bal;
        if (lane == 32) madj[wid * 4 + 2 * p + 1] = (unsigned)(bal >> 32);
    }
    short8_t Bf;
    #pragma unroll
    for (int jj = 0; jj < 8; ++jj)
        Bf[jj] = f2bf(We[(8 * g + jj) * MID_ + mt * 32 + lm]);

    f32x16 accm;
    #pragma unroll
    for (int r = 0; r < 16; ++r) accm[r] = -INFINITY;

    __syncthreads();

    if (t < 32) {
        unsigned ao = 0xFFFFFFFFu;
        #pragma unroll
        for (int i2 = 0; i2 < 32; ++i2) ao &= madj[i2];
        anyzf[t] = ((ao >> t) & 1u) ? -INFINITY : 0.0f;
    }

    const float* efr = ef + (((size_t)(b * N_ + i0 + ih * 16)) * N_ + j0 + lm) * FE + 8 * g;
    #pragma unroll 2
    for (int ii = 0; ii < 16; ++ii) {
        const int i_l = ih * 16 + ii;
        const float4 ea = *(const float4*)efr;
        const float4 eb = *(const float4*)(efr + 4);
        efr += (size_t)N_ * FE;
        short8_t Af;
        Af[0] = f2bf(ea.x); Af[1] = f2bf(ea.y); Af[2] = f2bf(ea.z); Af[3] = f2bf(ea.w);
        Af[4] = f2bf(eb.x); Af[5] = f2bf(eb.y); Af[6] = f2bf(eb.z); Af[7] = f2bf(eb.w);

        const unsigned vmg = madj[i_l] >> (4 * g);
        const float m2v = m2l[i_l * MID_ + mt * 32 + lm];
        f32x16 C;
        #pragma unroll
        for (int r = 0; r < 16; ++r) {
            const int cr = (r & 3) + 8 * (r >> 2);
            C[r] = (vmg & (1u << cr)) ? m2v : -INFINITY;
        }
        const f32x16 S = __builtin_amdgcn_mfma_f32_32x32x16_bf16(Af, Bf, C, 0, 0, 0);
        #pragma unroll
        for (int r = 0; r < 16; ++r) accm[r] = fmaxf(accm[r], S[r]);
    }

    if (ih == 1) {
        #pragma unroll
        for (int r = 0; r < 16; ++r) {
            const int jrow = (r & 3) + 8 * (r >> 2) + 4 * g;
            mtile[mt][jrow * 32 + lm] = accm[r];
        }
    }
    __syncthreads();
    float* ftile = m2l;
    if (ih == 0) {
        #pragma unroll
        for (int r = 0; r < 16; ++r) {
            const int jrow = (r & 3) + 8 * (r >> 2) + 4 * g;
            ftile[jrow * MID_ + mt * 32 + lm] = fmaxf(accm[r], mtile[mt][jrow * 32 + lm]);
        }
    }
    __syncthreads();

    {
        const int jrow = t >> 4, m0 = (t & 15) * 8;
        const float az = anyzf[jrow];
        const float*  c1  = msg1c + (size_t)(b * N_ + j0 + jrow) * MID_ + m0;
        float*        dst = part  + ((size_t)(ic * 2 + b) * N_ + j0 + jrow) * MID_ + m0;
        const float*  tl  = &ftile[jrow * MID_ + m0];
        const float4 c1a = *(const float4*)c1;
        const float4 c1b = *(const float4*)(c1 + 4);
        float4 o0, o1;
        o0.x = fmaxf(tl[0] + c1a.x, az);
        o0.y = fmaxf(tl[1] + c1a.y, az);
        o0.z = fmaxf(tl[2] + c1a.z, az);
        o0.w = fmaxf(tl[3] + c1a.w, az);
        o1.x = fmaxf(tl[4] + c1b.x, az);
        o1.y = fmaxf(tl[5] + c1b.y, az);
        o1.z = fmaxf(tl[6] + c1b.z, az);
        o1.w = fmaxf(tl[7] + c1b.w, az);
        *(float4*)dst       = o0;
        *(float4*)(dst + 4) = o1;
    }
}

__global__ __launch_bounds__(256, 2) void kC(
    const float* __restrict__ part, const float* __restrict__ h1,
    const float* __restrict__ Wo2, const float* __restrict__ bo2,
    float* __restrict__ out)
{
    __shared__ float ms[2 * MID_];
    const int bid = blockIdx.x;
    const int b   = bid >> 8;
    const int j0  = (bid & 255) * 2;
    const int t   = threadIdx.x;
    const int r   = t >> 7, m = t & 127;
    const size_t base = ((size_t)b * N_ + j0 + r) * MID_ + m;

    float u = -INFINITY;
    #pragma unroll
    for (int icc = 0; icc < 16; ++icc)
        u = fmaxf(u, part[(size_t)icc * 2 * N_ * MID_ + base]);
    ms[r * MID_ + m] = u;
    __syncthreads();

    float acc = h1[base] + bo2[m];
    for (int k0 = 0; k0 < MID_; k0 += 8) {
        float wv[8];
        #pragma unroll
        for (int uu = 0; uu < 8; ++uu) wv[uu] = Wo2[(k0 + uu) * MID_ + m];
        #pragma unroll
        for (int uu = 0; uu < 8; ++uu) acc += ms[r * MID_ + k0 + uu] * wv[uu];
    }
    out[base] = acc;
}

// ---------------------------------------------------------------------------
extern "C" void kernel_launch(void* const* d_in, const int* in_sizes, int n_in,
                              void* d_out, int out_size, void* d_ws, size_t ws_size,
                              hipStream_t stream)
{
    const float* feat = (const float*)d_in[0];
    const float* ef   = (const float*)d_in[1];
    const float* gf   = (const float*)d_in[2];
    const float* adj  = (const float*)d_in[3];
    const float* W1   = (const float*)d_in[4];
    const float* b1   = (const float*)d_in[5];
    const float* W2   = (const float*)d_in[6];
    const float* b2   = (const float*)d_in[7];
    const float* We   = (const float*)d_in[8];
    const float* be   = (const float*)d_in[9];
    const float* Wg   = (const float*)d_in[10];
    const float* bg   = (const float*)d_in[11];
    const float* Wo1  = (const float*)d_in[12];
    const float* bo1  = (const float*)d_in[13];
    const float* Wo2  = (const float*)d_in[14];
    const float* bo2  = (const float*)d_in[15];
    float* out = (float*)d_out;

    float* ws    = (float*)d_ws;
    float* msg1c = ws;                        // 131072 f32
    float* msg2  = ws + 131072;               // 131072 f32
    float* h1    = ws + 262144;               // 131072 f32
    float* part  = ws + 393216;               // 16ic*2b*512*128 f32 = 8 MB

    void* args[] = {
        (void*)&feat, (void*)&ef, (void*)&gf, (void*)&adj,
        (void*)&W1, (void*)&b1, (void*)&W2, (void*)&b2,
        (void*)&We, (void*)&be, (void*)&Wg, (void*)&bg,
        (void*)&Wo1, (void*)&bo1, (void*)&Wo2, (void*)&bo2,
        (void*)&msg1c, (void*)&msg2, (void*)&h1, (void*)&part, (void*)&out
    };
    hipError_t e = hipLaunchCooperativeKernel((const void*)kFused,
                                              dim3(512), dim3(256),
                                              args, 0, stream);
    if (e != hipSuccess) {
        // fallback: proven round-7 three-kernel path (identical outputs)
        hipLaunchKernelGGL(kA, dim3(512), dim3(256), 0, stream,
            feat, gf, W1, b1, W2, b2, be, Wg, bg, Wo1, bo1, msg1c, msg2, h1);
        hipLaunchKernelGGL(kB, dim3(512), dim3(512), 0, stream,
            ef, adj, We, msg1c, msg2, part);
        hipLaunchKernelGGL(kC, dim3(512), dim3(256), 0, stream,
            part, h1, Wo2, bo2, out);
    }
}

// Round 10
// 30.072 us; speedup vs baseline: 5.1367x; 5.1367x over previous
//
#include <hip/hip_runtime.h>
#include <hip/hip_bf16.h>
#include <math.h>

#define B_   2
#define N_   512
#define FN   128
#define FE   16
#define MID_ 128

typedef __attribute__((ext_vector_type(8)))  short short8_t;
typedef __attribute__((ext_vector_type(16))) float f32x16;

__device__ __forceinline__ short f2bf(float f) {
    __bf16 h = (__bf16)f;                    // fptrunc -> RNE bf16
    return __builtin_bit_cast(short, h);
}

// ---------------------------------------------------------------------------
// kA round 10: three feat@W GEMMs as one-wave 32x32 MFMA tiles.
// grid 386 x 64 thr: blocks 0..383 = 2b x 16nt(32 rows) x 12ct(3W x 4 col-tiles)
// *** round-9 bug: K stepped by 32 with 4 MFMAs -> only half of K=128 summed.
//     mfma_f32_32x32x16_bf16 contracts K=16/instr: need 8 steps of 16. ***
// blocks 384,385: msgg[b][m] = b1+be+bg + gfeat[b]@Wg.
// Fragment mappings identical to kB's (validated rounds 2-7).
// ---------------------------------------------------------------------------
__global__ __launch_bounds__(64) void kA(
    const float* __restrict__ feat, const float* __restrict__ gfeat,
    const float* __restrict__ W1, const float* __restrict__ b1,
    const float* __restrict__ W2, const float* __restrict__ be,
    const float* __restrict__ Wg, const float* __restrict__ bg,
    const float* __restrict__ Wo1,
    float* __restrict__ msg1c, float* __restrict__ msg2, float* __restrict__ h1,
    float* __restrict__ msgg)
{
    const int bid = blockIdx.x;
    const int t   = threadIdx.x;

    if (bid >= 384) {            // ---- msgg blocks (one per b) ----
        const int b = bid - 384;
        const float* gb = gfeat + b * FN;
        #pragma unroll
        for (int half = 0; half < 2; ++half) {
            const int m = t + 64 * half;
            float mg = b1[m] + be[m] + bg[m];
            for (int k0 = 0; k0 < FN; k0 += 16) {
                float wv[16];
                #pragma unroll
                for (int u = 0; u < 16; ++u) wv[u] = Wg[(k0 + u) * MID_ + m];
                #pragma unroll
                for (int u = 0; u < 16; ++u) mg += gb[k0 + u] * wv[u];
            }
            msgg[b * MID_ + m] = mg;
        }
        return;
    }

    // ---- GEMM tile blocks ----
    const int bb  = bid / 192;               // batch
    const int rem = bid - bb * 192;
    const int nt  = rem / 12;                // row tile (32 rows)
    const int ct  = rem - nt * 12;           // 0..11
    const int w   = ct >> 2;                 // which W
    const int c0  = (ct & 3) * 32;           // col base
    const int n0  = nt * 32;
    const int g   = t >> 5, lm = t & 31;

    const float* Ws  = (w == 0) ? W1    : (w == 1) ? W2   : Wo1;
    float*       dst = (w == 0) ? msg1c : (w == 1) ? msg2 : h1;

    // A fragments: feat rows, 8 K-steps x 16 (lane k = ks*16 + 8g + j)
    short8_t Af[8];
    #pragma unroll
    for (int ks = 0; ks < 8; ++ks) {
        const float* ap = feat + (size_t)(bb * N_ + n0 + lm) * FN + ks * 16 + 8 * g;
        const float4 a0 = *(const float4*)ap;
        const float4 a1 = *(const float4*)(ap + 4);
        short8_t A;
        A[0] = f2bf(a0.x); A[1] = f2bf(a0.y); A[2] = f2bf(a0.z); A[3] = f2bf(a0.w);
        A[4] = f2bf(a1.x); A[5] = f2bf(a1.y); A[6] = f2bf(a1.z); A[7] = f2bf(a1.w);
        Af[ks] = A;
    }
    // B fragments: W columns (32-lane coalesced 128B rows)
    short8_t Bfr[8];
    #pragma unroll
    for (int ks = 0; ks < 8; ++ks) {
        short8_t Bv;
        #pragma unroll
        for (int j = 0; j < 8; ++j)
            Bv[j] = f2bf(Ws[(size_t)(ks * 16 + 8 * g + j) * MID_ + c0 + lm]);
        Bfr[ks] = Bv;
    }

    f32x16 acc;
    #pragma unroll
    for (int r = 0; r < 16; ++r) acc[r] = 0.0f;
    #pragma unroll
    for (int ks = 0; ks < 8; ++ks)
        acc = __builtin_amdgcn_mfma_f32_32x32x16_bf16(Af[ks], Bfr[ks], acc, 0, 0, 0);

    #pragma unroll
    for (int r = 0; r < 16; ++r) {
        const int row = (r & 3) + 8 * (r >> 2) + 4 * g;
        dst[(size_t)(bb * N_ + n0 + row) * MID_ + c0 + lm] = acc[r];
    }
}

// ---------------------------------------------------------------------------
// kB: r7 body (spill-free, 8 waves = 4mt x 2ih, ef direct global->reg,
// ballot masks -> C-seed, pairwise LDS merge). m2v += b2 (msg2 raw);
// epilogue adds msgg (msg1c raw). grid 512 = 2b x 16jt x 16ic; block 512.
// (byte-identical to round 9)
// ---------------------------------------------------------------------------
__global__ __launch_bounds__(512, 4) void kB(
    const float* __restrict__ ef, const float* __restrict__ adj,
    const float* __restrict__ We, const float* __restrict__ b2,
    const float* __restrict__ msg1c, const float* __restrict__ msg2,
    const float* __restrict__ msgg,
    float* __restrict__ part)
{
    __shared__ float    m2l[32 * MID_];    // 16 KB; reused as final tile after merge
    __shared__ float    mtile[4][32 * 32]; // 16 KB ih=1 partials
    __shared__ unsigned madj[32];
    __shared__ float    anyzf[32];

    const int bid = blockIdx.x;            // 512 = 2b * 16jt * 16ic
    const int b   = bid >> 8;
    const int jt  = (bid >> 4) & 15;
    const int ic  = bid & 15;
    const int j0  = jt * 32, i0 = ic * 32;
    const int t    = threadIdx.x;
    const int lane = t & 63, wid = t >> 6;
    const int mt   = wid & 3, ih = wid >> 2;
    const int g    = lane >> 5, lm = lane & 31;

    // stage msg2 chunk [32 i][128 m] (coalesced)
    {
        const float4* src = (const float4*)(msg2 + (size_t)(b * N_ + i0) * MID_);
        ((float4*)m2l)[t]       = src[t];
        ((float4*)m2l)[t + 512] = src[t + 512];
    }
    // adj -> bitmasks via ballot (wave covers 4 i via 2 ballots)
    #pragma unroll
    for (int p = 0; p < 2; ++p) {
        const int i_l = wid * 4 + 2 * p + g;
        const float av = adj[(size_t)(b * N_ + i0 + i_l) * N_ + j0 + lm];
        const unsigned long long bal = __ballot(av != 0.0f);
        if (lane == 0)  madj[wid * 4 + 2 * p]     = (unsigned)bal;
        if (lane == 32) madj[wid * 4 + 2 * p + 1] = (unsigned)(bal >> 32);
    }
    // B fragment for this wave's mt: We[k=8g+jj, mt*32+lm]
    short8_t Bf;
    #pragma unroll
    for (int jj = 0; jj < 8; ++jj)
        Bf[jj] = f2bf(We[(8 * g + jj) * MID_ + mt * 32 + lm]);
    const float b2v = b2[mt * 32 + lm];    // msg2 is raw now

    f32x16 accm;
    #pragma unroll
    for (int r = 0; r < 16; ++r) accm[r] = -INFINITY;

    __syncthreads();

    if (t < 32) {   // all-ones column -> -inf floor, else 0 (read in epilogue)
        unsigned ao = 0xFFFFFFFFu;
        #pragma unroll
        for (int i2 = 0; i2 < 32; ++i2) ao &= madj[i2];
        anyzf[t] = ((ao >> t) & 1u) ? -INFINITY : 0.0f;
    }

    // main loop: this wave's 16 i's, one mt
    const float* efr = ef + (((size_t)(b * N_ + i0 + ih * 16)) * N_ + j0 + lm) * FE + 8 * g;
    #pragma unroll 2
    for (int ii = 0; ii < 16; ++ii) {
        const int i_l = ih * 16 + ii;
        const float4 ea = *(const float4*)efr;
        const float4 eb = *(const float4*)(efr + 4);
        efr += (size_t)N_ * FE;
        short8_t Af;
        Af[0] = f2bf(ea.x); Af[1] = f2bf(ea.y); Af[2] = f2bf(ea.z); Af[3] = f2bf(ea.w);
        Af[4] = f2bf(eb.x); Af[5] = f2bf(eb.y); Af[6] = f2bf(eb.z); Af[7] = f2bf(eb.w);

        const unsigned vmg = madj[i_l] >> (4 * g);
        const float m2v = m2l[i_l * MID_ + mt * 32 + lm] + b2v;
        f32x16 C;
        #pragma unroll
        for (int r = 0; r < 16; ++r) {
            const int cr = (r & 3) + 8 * (r >> 2);
            C[r] = (vmg & (1u << cr)) ? m2v : -INFINITY;
        }
        const f32x16 S = __builtin_amdgcn_mfma_f32_32x32x16_bf16(Af, Bf, C, 0, 0, 0);
        #pragma unroll
        for (int r = 0; r < 16; ++r) accm[r] = fmaxf(accm[r], S[r]);
    }

    // pairwise cross-wave merge (no atomics)
    if (ih == 1) {
        #pragma unroll
        for (int r = 0; r < 16; ++r) {
            const int jrow = (r & 3) + 8 * (r >> 2) + 4 * g;
            mtile[mt][jrow * 32 + lm] = accm[r];
        }
    }
    __syncthreads();   // mtile ready; all m2l reads done -> safe to reuse as ftile
    float* ftile = m2l;
    if (ih == 0) {
        #pragma unroll
        for (int r = 0; r < 16; ++r) {
            const int jrow = (r & 3) + 8 * (r >> 2) + 4 * g;
            ftile[jrow * MID_ + mt * 32 + lm] = fmaxf(accm[r], mtile[mt][jrow * 32 + lm]);
        }
    }
    __syncthreads();

    // epilogue: + (msg1c_raw + msgg), 0-floor, coalesced f32 store
    {
        const int jrow = t >> 4, m0 = (t & 15) * 8;
        const float az = anyzf[jrow];
        const float*  c1  = msg1c + (size_t)(b * N_ + j0 + jrow) * MID_ + m0;
        const float*  gg  = msgg + b * MID_ + m0;
        float*        dst = part  + ((size_t)(ic * 2 + b) * N_ + j0 + jrow) * MID_ + m0;
        const float*  tl  = &ftile[jrow * MID_ + m0];
        const float4 c1a = *(const float4*)c1;
        const float4 c1b = *(const float4*)(c1 + 4);
        const float4 g1a = *(const float4*)gg;
        const float4 g1b = *(const float4*)(gg + 4);
        float4 o0, o1;
        o0.x = fmaxf(tl[0] + c1a.x + g1a.x, az);
        o0.y = fmaxf(tl[1] + c1a.y + g1a.y, az);
        o0.z = fmaxf(tl[2] + c1a.z + g1a.z, az);
        o0.w = fmaxf(tl[3] + c1a.w + g1a.w, az);
        o1.x = fmaxf(tl[4] + c1b.x + g1b.x, az);
        o1.y = fmaxf(tl[5] + c1b.y + g1b.y, az);
        o1.z = fmaxf(tl[6] + c1b.z + g1b.z, az);
        o1.w = fmaxf(tl[7] + c1b.w + g1b.w, az);
        *(float4*)dst       = o0;
        *(float4*)(dst + 4) = o1;
    }
}

// ---------------------------------------------------------------------------
// kC: msgs = max over 16 f32 partials; out = (h1_raw + bo1) + msgs@Wo2 + bo2
// grid 512 = 2b x 256jt (2 rows); block 256 (byte-identical to round 9)
// ---------------------------------------------------------------------------
__global__ __launch_bounds__(256, 2) void kC(
    const float* __restrict__ part, const float* __restrict__ h1,
    const float* __restrict__ Wo2, const float* __restrict__ bo1,
    const float* __restrict__ bo2,
    float* __restrict__ out)
{
    __shared__ float ms[2 * MID_];
    const int bid = blockIdx.x;          // 512 = 2b * 256 tiles
    const int b   = bid >> 8;
    const int j0  = (bid & 255) * 2;
    const int t   = threadIdx.x;
    const int r   = t >> 7, m = t & 127;
    const size_t base = ((size_t)b * N_ + j0 + r) * MID_ + m;

    float u = -INFINITY;
    #pragma unroll
    for (int icc = 0; icc < 16; ++icc)
        u = fmaxf(u, part[(size_t)icc * 2 * N_ * MID_ + base]);
    ms[r * MID_ + m] = u;
    __syncthreads();

    float acc = h1[base] + bo1[m] + bo2[m];
    for (int k0 = 0; k0 < MID_; k0 += 8) {
        float wv[8];
        #pragma unroll
        for (int uu = 0; uu < 8; ++uu) wv[uu] = Wo2[(k0 + uu) * MID_ + m];
        #pragma unroll
        for (int uu = 0; uu < 8; ++uu) acc += ms[r * MID_ + k0 + uu] * wv[uu];
    }
    out[base] = acc;
}

// ---------------------------------------------------------------------------
extern "C" void kernel_launch(void* const* d_in, const int* in_sizes, int n_in,
                              void* d_out, int out_size, void* d_ws, size_t ws_size,
                              hipStream_t stream)
{
    const float* feat = (const float*)d_in[0];
    const float* ef   = (const float*)d_in[1];
    const float* gf   = (const float*)d_in[2];
    const float* adj  = (const float*)d_in[3];
    const float* W1   = (const float*)d_in[4];
    const float* b1   = (const float*)d_in[5];
    const float* W2   = (const float*)d_in[6];
    const float* b2   = (const float*)d_in[7];
    const float* We   = (const float*)d_in[8];
    const float* be   = (const float*)d_in[9];
    const float* Wg   = (const float*)d_in[10];
    const float* bg   = (const float*)d_in[11];
    const float* Wo1  = (const float*)d_in[12];
    const float* bo1  = (const float*)d_in[13];
    const float* Wo2  = (const float*)d_in[14];
    const float* bo2  = (const float*)d_in[15];
    float* out = (float*)d_out;

    float* ws    = (float*)d_ws;
    float* msg1c = ws;                        // 131072 f32 (raw feat@W1)
    float* msg2  = ws + 131072;               // 131072 f32 (raw feat@W2)
    float* h1    = ws + 262144;               // 131072 f32 (raw feat@Wo1)
    float* part  = ws + 393216;               // 16ic*2b*512*128 f32 = 8 MB
    float* msgg  = ws + 393216 + 2097152;     // 256 f32

    hipLaunchKernelGGL(kA, dim3(386), dim3(64), 0, stream,
        feat, gf, W1, b1, W2, be, Wg, bg, Wo1, msg1c, msg2, h1, msgg);
    hipLaunchKernelGGL(kB, dim3(512), dim3(512), 0, stream,
        ef, adj, We, b2, msg1c, msg2, msgg, part);
    hipLaunchKernelGGL(kC, dim3(512), dim3(256), 0, stream,
        part, h1, Wo2, bo1, bo2, out);
}